// Round 6
// baseline (357.034 us; speedup 1.0000x reference)
//
#include <hip/hip_runtime.h>
#include <math.h>

#define NB 512
#define CHN 5

static constexpr int kN = 512 * 512;        // 262144 pixels
static constexpr int kB = 16;
static constexpr int kChunks = 32;
static constexpr int kThreads1 = 1024;
static constexpr int kPixPerBlock = kN / kChunks;            // 8192
static constexpr int kF4PerBlock = kPixPerBlock / 4;         // 2048
static constexpr int kGroups = kF4PerBlock / kThreads1;      // 2 per thread
static constexpr int kHist = CHN * NB;                       // 2560 bins per batch

// workspace layout (bytes):
//   [0, 16*32*16*4)       : float    spart[16][32][16]            (32 KB)
//   [+ , +16*32*2560*2)   : ushort   part_hist[16][32][2560]      (2.62 MB)
//   [+ , +16*4)           : unsigned tickets[16]
static constexpr size_t SPART_OFF = 0;
static constexpr size_t PART_OFF  = SPART_OFF + (size_t)kB * kChunks * 16 * 4;
static constexpr size_t TICK_OFF  = PART_OFF + (size_t)kB * kChunks * kHist * 2;

// Fused: per-chunk histogram+scalar pass; the LAST block to finish a batch
// (dynamic, via device-scope ticket) runs that batch's finalize inline.
__global__ __launch_bounds__(kThreads1) void ep_fused(
    const float* __restrict__ logits,
    const float* __restrict__ sevmap,
    const float* __restrict__ mask,
    float* __restrict__ spart,
    unsigned short* __restrict__ part_hist,
    unsigned* __restrict__ tickets,
    const float* __restrict__ ln_w, const float* __restrict__ ln_b,
    const float* __restrict__ w1, const float* __restrict__ b1,
    const float* __restrict__ w2, const float* __restrict__ b2,
    float* __restrict__ out) {
  __shared__ __align__(16) unsigned s_hcnt[kHist];  // 10 KB; reused as merged hist
  __shared__ float s_red[16][16];
  __shared__ float s_scal[16];
  __shared__ float topk[8];
  __shared__ float stats[18], normed[18], h1v[256];
  __shared__ unsigned s_islast;

  const int tid = threadIdx.x;
  const int lane = tid & 63;
  const int wv = tid >> 6;
  const int b = blockIdx.y;
  const int chunk = blockIdx.x;

  for (int i = tid; i < kHist; i += kThreads1) s_hcnt[i] = 0u;
  __syncthreads();

  const float4* L0 = (const float4*)(logits + (size_t)b * 4 * kN);
  const float4* L1 = L0 + kN / 4;
  const float4* L2 = L1 + kN / 4;
  const float4* L3 = L2 + kN / 4;
  const float4* SV = (const float4*)(sevmap + (size_t)b * kN);
  const float4* MK = (const float4*)(mask + (size_t)b * kN);
  const int base = chunk * kF4PerBlock;

  float cnt = 0.f, sum0 = 0.f, sum1 = 0.f, sum2 = 0.f, sum3 = 0.f;
  float sevs = 0.f, dmg = 0.f, hig = 0.f;
  float mx0 = 0.f, mx1 = 0.f, mx2 = 0.f, mx3 = 0.f, sevm = 0.f;

#pragma unroll
  for (int g = 0; g < kGroups; ++g) {
    const int fi = base + g * kThreads1 + tid;
    float4 a = L0[fi];
    float4 bq = L1[fi];
    float4 cq = L2[fi];
    float4 dq = L3[fi];
    float4 sv = SV[fi];
    float4 mk = MK[fi];
#pragma unroll
    for (int j = 0; j < 4; ++j) {
      float l0 = ((const float*)&a)[j];
      float l1 = ((const float*)&bq)[j];
      float l2 = ((const float*)&cq)[j];
      float l3 = ((const float*)&dq)[j];
      // |logit| < ~6 for N(0,1) inputs -> exp safe without max-subtraction
      float e0 = __expf(l0);
      float e1 = __expf(l1);
      float e2 = __expf(l2);
      float e3 = __expf(l3);
      float inv = 1.f / (e0 + e1 + e2 + e3);
      float p0 = e0 * inv, p1 = e1 * inv, p2 = e2 * inv, p3 = e3 * inv;
      float sg = 1.f / (1.f + __expf(-((const float*)&sv)[j]));
      bool valid = ((const float*)&mk)[j] > 0.5f;
      if (valid) {
        cnt += 1.f;
        sum0 += p0; sum1 += p1; sum2 += p2; sum3 += p3;
        mx0 = fmaxf(mx0, p0); mx1 = fmaxf(mx1, p1);
        mx2 = fmaxf(mx2, p2); mx3 = fmaxf(mx3, p3);
        sevs += sg; sevm = fmaxf(sevm, sg);
        dmg += (p1 + p2 + p3 > 0.25f) ? 1.f : 0.f;
        hig += (p2 + p3 > 0.25f) ? 1.f : 0.f;
        int bi0 = min(NB - 1, (int)(p0 * (float)NB));
        int bi1 = min(NB - 1, (int)(p1 * (float)NB));
        int bi2 = min(NB - 1, (int)(p2 * (float)NB));
        int bi3 = min(NB - 1, (int)(p3 * (float)NB));
        int bi4 = min(NB - 1, (int)(sg * (float)NB));
        atomicAdd(&s_hcnt[0 * NB + bi0], 1u);
        atomicAdd(&s_hcnt[1 * NB + bi1], 1u);
        atomicAdd(&s_hcnt[2 * NB + bi2], 1u);
        atomicAdd(&s_hcnt[3 * NB + bi3], 1u);
        atomicAdd(&s_hcnt[4 * NB + bi4], 1u);
      }
    }
  }

  // wave-level reduction of the 13 scalar stats
  float acc[8] = {cnt, sum0, sum1, sum2, sum3, sevs, dmg, hig};
  float mxs[5] = {mx0, mx1, mx2, mx3, sevm};
#pragma unroll
  for (int off = 32; off > 0; off >>= 1) {
#pragma unroll
    for (int i = 0; i < 8; ++i) acc[i] += __shfl_down(acc[i], off);
#pragma unroll
    for (int i = 0; i < 5; ++i) mxs[i] = fmaxf(mxs[i], __shfl_down(mxs[i], off));
  }
  if (lane == 0) {
#pragma unroll
    for (int i = 0; i < 8; ++i) s_red[wv][i] = acc[i];
#pragma unroll
    for (int i = 0; i < 5; ++i) s_red[wv][8 + i] = mxs[i];
  }
  __syncthreads();
  if (tid < 16) {
    float v;
    if (tid < 8) {
      v = 0.f;
#pragma unroll
      for (int w = 0; w < 16; ++w) v += s_red[w][tid];
    } else if (tid < 13) {
      v = 0.f;
#pragma unroll
      for (int w = 0; w < 16; ++w) v = fmaxf(v, s_red[w][tid]);
    } else {
      v = 0.f;
    }
    spart[((size_t)b * kChunks + chunk) * 16 + tid] = v;  // plain store
  }

  // store partial histogram as ushort (max count/block = 8192 < 65536)
  {
    ushort4* dst = (ushort4*)(part_hist + ((size_t)b * kChunks + chunk) * kHist);
    for (int i = tid; i < kHist / 4; i += kThreads1) {
      ushort4 v;
      v.x = (unsigned short)s_hcnt[4 * i + 0];
      v.y = (unsigned short)s_hcnt[4 * i + 1];
      v.z = (unsigned short)s_hcnt[4 * i + 2];
      v.w = (unsigned short)s_hcnt[4 * i + 3];
      dst[i] = v;
    }
  }

  // ---- dynamic last-block handoff (device-scope) ----
  __threadfence();   // release: make this block's stores visible device-wide
  __syncthreads();
  if (tid == 0) {
    unsigned prev = atomicAdd(&tickets[b], 1u);
    s_islast = (prev == (unsigned)(kChunks - 1)) ? 1u : 0u;
  }
  __syncthreads();
  if (!s_islast) return;
  __threadfence();   // acquire: see all other blocks' partials

  // ================= finalize for batch b (last block only) =================
  if (tid < 8) topk[tid] = 0.f;

  // Phase A: merge 32 ushort partials into s_hcnt (reused as merged hist).
  {
    const unsigned* pp = (const unsigned*)(part_hist + (size_t)b * kChunks * kHist);
    for (int i = tid; i < kHist / 2; i += kThreads1) {
      unsigned a0 = 0, a1 = 0;
#pragma unroll
      for (int c = 0; c < kChunks; ++c) {
        unsigned u = pp[(size_t)c * (kHist / 2) + i];
        a0 += u & 0xffffu;
        a1 += u >> 16;
      }
      s_hcnt[2 * i] = a0;
      s_hcnt[2 * i + 1] = a1;
    }
  }

  // Phase C (wave 15): reduce the 13 scalar stats over 32 partials
  if (wv == 15 && lane < kChunks) {
    for (int s = 0; s < 13; ++s) {
      float v = spart[((size_t)b * kChunks + lane) * 16 + s];
#pragma unroll
      for (int off = 16; off > 0; off >>= 1) {
        float t = __shfl_down(v, off, 32);
        v = (s < 8) ? (v + t) : fmaxf(v, t);
      }
      if (lane == 0) s_scal[s] = v;
    }
  }
  __syncthreads();

  const float total = s_scal[0];
  const bool has = total > 0.f;
  const float safe = fmaxf(total, 1.f);
  const float kf = fmaxf(1.f, rintf(total * 0.1f));

  // Phase B: waves 0..4 each scan one channel's 512 bins from LDS.
  // lane owns 8 bins [base, base+7], base=(63-lane)*8 -> ascending lane =
  // descending value range.
  if (wv < CHN) {
    const int c = wv;
    const int base2 = (63 - lane) * 8;
    float cntv[8];
    float gc = 0.f, gs = 0.f;
    const uint4* hv = (const uint4*)s_hcnt;
#pragma unroll
    for (int q = 0; q < 2; ++q) {
      uint4 u = hv[c * (NB / 4) + (63 - lane) * 2 + q];
      float c0 = (float)u.x, c1 = (float)u.y, c2 = (float)u.z, c3 = (float)u.w;
      int bin = base2 + q * 4;
      cntv[q * 4 + 0] = c0; cntv[q * 4 + 1] = c1;
      cntv[q * 4 + 2] = c2; cntv[q * 4 + 3] = c3;
      gc += c0 + c1 + c2 + c3;
      gs += c0 * ((bin + 0.5f) * (1.f / NB)) + c1 * ((bin + 1.5f) * (1.f / NB)) +
            c2 * ((bin + 2.5f) * (1.f / NB)) + c3 * ((bin + 3.5f) * (1.f / NB));
    }
    // inclusive scan over lanes (lane 0 = topmost bins)
    float ic = gc, is = gs;
#pragma unroll
    for (int off = 1; off < 64; off <<= 1) {
      float tc = __shfl_up(ic, off);
      float ts = __shfl_up(is, off);
      if (lane >= off) { ic += tc; is += ts; }
    }
    float ec = ic - gc;   // count strictly above this lane's bins
    float es = is - gs;   // center-weighted sum strictly above

    if (has && ec < kf && kf <= ic) {
      float cg = ec, ss = es;
#pragma unroll
      for (int d = 7; d >= 0; --d) {
        int bin = base2 + d;
        float center = (bin + 0.5f) * (1.f / NB);
        float cb = cntv[d];
        if (cg + cb >= kf) {
          float r = kf - cg;
          topk[c] = (ss + r * center) / kf;
          break;
        }
        cg += cb;
        ss += cb * center;
      }
    }
  }
  __syncthreads();

  if (tid == 0) {
    float inv_safe = 1.f / safe;
    stats[0] = s_scal[1] * inv_safe;
    stats[1] = s_scal[2] * inv_safe;
    stats[2] = s_scal[3] * inv_safe;
    stats[3] = s_scal[4] * inv_safe;
#pragma unroll
    for (int c = 0; c < 4; ++c) stats[4 + c] = has ? s_scal[8 + c] : 0.f;
#pragma unroll
    for (int c = 0; c < 4; ++c) stats[8 + c] = has ? topk[c] : 0.f;
    stats[12] = has ? s_scal[5] * inv_safe : 0.f;
    stats[13] = has ? s_scal[12] : 0.f;
    stats[14] = has ? topk[4] : 0.f;
    stats[15] = has ? s_scal[6] * inv_safe : 0.f;
    stats[16] = has ? s_scal[7] * inv_safe : 0.f;
    stats[17] = has ? total * (1.f / (float)kN) : 0.f;

    float mu = 0.f;
#pragma unroll
    for (int i = 0; i < 18; ++i) mu += stats[i];
    mu *= (1.f / 18.f);
    float var = 0.f;
#pragma unroll
    for (int i = 0; i < 18; ++i) {
      float d = stats[i] - mu;
      var += d * d;
    }
    var *= (1.f / 18.f);
    float inv_std = rsqrtf(var + 1e-5f);
#pragma unroll
    for (int i = 0; i < 18; ++i)
      normed[i] = (stats[i] - mu) * inv_std * ln_w[i] + ln_b[i];
  }
  __syncthreads();

  // Phase D (threads 0..255): MLP
  if (tid < 256) {
    float x = b1[tid];
#pragma unroll
    for (int i = 0; i < 18; ++i) x += normed[i] * w1[i * 256 + tid];
    h1v[tid] = 0.5f * x * (1.f + erff(x * 0.70710678118654752440f));
  }
  __syncthreads();
  if (tid < 256) {
    float y = b2[tid];
    for (int i = 0; i < 256; ++i) y += h1v[i] * w2[i * 256 + tid];

    // outputs: stats[16][18] | projected[16][256] | damaged[16] | high[16] | tar[16]
    out[288 + b * 256 + tid] = y;
    if (tid < 18) out[b * 18 + tid] = stats[tid];
    if (tid == 0) {
      out[4384 + b] = stats[15];
      out[4400 + b] = stats[16];
      out[4416 + b] = stats[17];
    }
  }
}

extern "C" void kernel_launch(void* const* d_in, const int* in_sizes, int n_in,
                              void* d_out, int out_size, void* d_ws, size_t ws_size,
                              hipStream_t stream) {
  const float* logits = (const float*)d_in[0];
  const float* sevmap = (const float*)d_in[1];
  const float* maskp  = (const float*)d_in[2];
  const float* ln_w   = (const float*)d_in[3];
  const float* ln_b   = (const float*)d_in[4];
  const float* w1     = (const float*)d_in[5];
  const float* b1     = (const float*)d_in[6];
  const float* w2     = (const float*)d_in[7];
  const float* b2     = (const float*)d_in[8];
  float* out = (float*)d_out;

  char* ws = (char*)d_ws;
  float* spart = (float*)(ws + SPART_OFF);
  unsigned short* part_hist = (unsigned short*)(ws + PART_OFF);
  unsigned* tickets = (unsigned*)(ws + TICK_OFF);

  // zero the per-batch tickets (ws is poisoned 0xAA before every call)
  hipMemsetAsync(tickets, 0, kB * sizeof(unsigned), stream);

  dim3 g1(kChunks, kB);
  ep_fused<<<g1, kThreads1, 0, stream>>>(logits, sevmap, maskp, spart, part_hist,
                                         tickets, ln_w, ln_b, w1, b1, w2, b2, out);
}

// Round 7
// 150.898 us; speedup vs baseline: 2.3661x; 2.3661x over previous
//
#include <hip/hip_runtime.h>
#include <math.h>

#define NB 512
#define CHN 5

static constexpr int kN = 512 * 512;        // 262144 pixels
static constexpr int kB = 16;
static constexpr int kChunks = 32;
static constexpr int kThreads1 = 1024;
static constexpr int kPixPerBlock = kN / kChunks;            // 8192
static constexpr int kF4PerBlock = kPixPerBlock / 4;         // 2048
static constexpr int kGroups = kF4PerBlock / kThreads1;      // 2 per thread
static constexpr int kHist = CHN * NB;                       // 2560 bins per batch

// workspace layout (bytes):
//   [0, 16*32*16*4)       : float    spart[16][32][16]            (32 KB)
//   [+ , +16*32*2560*2)   : ushort   part_hist[16][32][2560]      (2.62 MB)
static constexpr size_t SPART_OFF = 0;
static constexpr size_t PART_OFF  = SPART_OFF + (size_t)kB * kChunks * 16 * 4;

// NOTE (R6 lesson): do NOT fuse finalize into pass1 via last-block ticket —
// the required device-scope fences trigger per-block L2 writeback/invalidate
// on this 8-XCD part (non-coherent per-XCD L2) and cost ~260 us. The
// two-kernel stream-ordered handoff amortizes the L2 flush once at the
// kernel boundary.

__global__ __launch_bounds__(kThreads1) void ep_pass1(
    const float* __restrict__ logits,
    const float* __restrict__ sevmap,
    const float* __restrict__ mask,
    float* __restrict__ spart,
    unsigned short* __restrict__ part_hist) {
  __shared__ unsigned s_hcnt[kHist];   // 10 KB
  __shared__ float s_red[16][16];

  const int tid = threadIdx.x;
  const int b = blockIdx.y;
  const int chunk = blockIdx.x;

  for (int i = tid; i < kHist; i += kThreads1) s_hcnt[i] = 0u;
  __syncthreads();

  const float4* L0 = (const float4*)(logits + (size_t)b * 4 * kN);
  const float4* L1 = L0 + kN / 4;
  const float4* L2 = L1 + kN / 4;
  const float4* L3 = L2 + kN / 4;
  const float4* SV = (const float4*)(sevmap + (size_t)b * kN);
  const float4* MK = (const float4*)(mask + (size_t)b * kN);
  const int base = chunk * kF4PerBlock;

  float cnt = 0.f, sum0 = 0.f, sum1 = 0.f, sum2 = 0.f, sum3 = 0.f;
  float sevs = 0.f, dmg = 0.f, hig = 0.f;
  float mx0 = 0.f, mx1 = 0.f, mx2 = 0.f, mx3 = 0.f, sevm = 0.f;

#pragma unroll
  for (int g = 0; g < kGroups; ++g) {
    const int fi = base + g * kThreads1 + tid;
    float4 a = L0[fi];
    float4 bq = L1[fi];
    float4 cq = L2[fi];
    float4 dq = L3[fi];
    float4 sv = SV[fi];
    float4 mk = MK[fi];
#pragma unroll
    for (int j = 0; j < 4; ++j) {
      float l0 = ((const float*)&a)[j];
      float l1 = ((const float*)&bq)[j];
      float l2 = ((const float*)&cq)[j];
      float l3 = ((const float*)&dq)[j];
      // |logit| < ~6 for N(0,1) inputs -> exp safe without max-subtraction
      float e0 = __expf(l0);
      float e1 = __expf(l1);
      float e2 = __expf(l2);
      float e3 = __expf(l3);
      float inv = 1.f / (e0 + e1 + e2 + e3);
      float p0 = e0 * inv, p1 = e1 * inv, p2 = e2 * inv, p3 = e3 * inv;
      float sg = 1.f / (1.f + __expf(-((const float*)&sv)[j]));
      bool valid = ((const float*)&mk)[j] > 0.5f;
      if (valid) {
        cnt += 1.f;
        sum0 += p0; sum1 += p1; sum2 += p2; sum3 += p3;
        mx0 = fmaxf(mx0, p0); mx1 = fmaxf(mx1, p1);
        mx2 = fmaxf(mx2, p2); mx3 = fmaxf(mx3, p3);
        sevs += sg; sevm = fmaxf(sevm, sg);
        dmg += (p1 + p2 + p3 > 0.25f) ? 1.f : 0.f;
        hig += (p2 + p3 > 0.25f) ? 1.f : 0.f;
        int bi0 = min(NB - 1, (int)(p0 * (float)NB));
        int bi1 = min(NB - 1, (int)(p1 * (float)NB));
        int bi2 = min(NB - 1, (int)(p2 * (float)NB));
        int bi3 = min(NB - 1, (int)(p3 * (float)NB));
        int bi4 = min(NB - 1, (int)(sg * (float)NB));
        atomicAdd(&s_hcnt[0 * NB + bi0], 1u);
        atomicAdd(&s_hcnt[1 * NB + bi1], 1u);
        atomicAdd(&s_hcnt[2 * NB + bi2], 1u);
        atomicAdd(&s_hcnt[3 * NB + bi3], 1u);
        atomicAdd(&s_hcnt[4 * NB + bi4], 1u);
      }
    }
  }

  // wave-level reduction of the 13 scalar stats (NO global atomics)
  float acc[8] = {cnt, sum0, sum1, sum2, sum3, sevs, dmg, hig};
  float mxs[5] = {mx0, mx1, mx2, mx3, sevm};
#pragma unroll
  for (int off = 32; off > 0; off >>= 1) {
#pragma unroll
    for (int i = 0; i < 8; ++i) acc[i] += __shfl_down(acc[i], off);
#pragma unroll
    for (int i = 0; i < 5; ++i) mxs[i] = fmaxf(mxs[i], __shfl_down(mxs[i], off));
  }
  const int lane = tid & 63;
  const int wv = tid >> 6;
  if (lane == 0) {
#pragma unroll
    for (int i = 0; i < 8; ++i) s_red[wv][i] = acc[i];
#pragma unroll
    for (int i = 0; i < 5; ++i) s_red[wv][8 + i] = mxs[i];
  }
  __syncthreads();
  if (tid < 16) {
    float v;
    if (tid < 8) {
      v = 0.f;
#pragma unroll
      for (int w = 0; w < 16; ++w) v += s_red[w][tid];
    } else if (tid < 13) {
      v = 0.f;
#pragma unroll
      for (int w = 0; w < 16; ++w) v = fmaxf(v, s_red[w][tid]);
    } else {
      v = 0.f;
    }
    spart[((size_t)b * kChunks + chunk) * 16 + tid] = v;  // plain store
  }

  // store partial histogram as ushort (max count/block = 8192 < 65536),
  // packed 4 bins -> 8 B stores
  ushort4* dst = (ushort4*)(part_hist + ((size_t)b * kChunks + chunk) * kHist);
  for (int i = tid; i < kHist / 4; i += kThreads1) {
    ushort4 v;
    v.x = (unsigned short)s_hcnt[4 * i + 0];
    v.y = (unsigned short)s_hcnt[4 * i + 1];
    v.z = (unsigned short)s_hcnt[4 * i + 2];
    v.w = (unsigned short)s_hcnt[4 * i + 3];
    dst[i] = v;
  }
}

__global__ __launch_bounds__(1024) void ep_finalize(
    const float* __restrict__ spart,
    const unsigned short* __restrict__ part_hist,
    const float* __restrict__ ln_w, const float* __restrict__ ln_b,
    const float* __restrict__ w1, const float* __restrict__ b1,
    const float* __restrict__ w2, const float* __restrict__ b2,
    float* __restrict__ out) {
  __shared__ unsigned s_hist[kHist];   // 10 KB, merged histogram for batch b
  __shared__ float topk[8];
  __shared__ float s_scal[16];
  __shared__ float stats[18], normed[18], h1v[256];

  const int tid = threadIdx.x;
  const int lane = tid & 63;
  const int wv = tid >> 6;
  const int b = blockIdx.x;

  if (tid < 8) topk[tid] = 0.f;

  // Phase A (all waves): merge 32 ushort partials into LDS uint histogram.
  // Read bin-pairs as uint: 1280 pairs per chunk, stride kHist/2 uints.
  {
    const unsigned* pp = (const unsigned*)(part_hist + (size_t)b * kChunks * kHist);
    for (int i = tid; i < kHist / 2; i += 1024) {
      unsigned a0 = 0, a1 = 0;
#pragma unroll
      for (int c = 0; c < kChunks; ++c) {
        unsigned u = pp[(size_t)c * (kHist / 2) + i];
        a0 += u & 0xffffu;
        a1 += u >> 16;
      }
      s_hist[2 * i] = a0;
      s_hist[2 * i + 1] = a1;
    }
  }

  // Phase C (wave 15, concurrent with A's tail): reduce the 13 scalar stats
  // over kChunks=32 partials (lanes 0..31)
  if (wv == 15 && lane < kChunks) {
    for (int s = 0; s < 13; ++s) {
      float v = spart[((size_t)b * kChunks + lane) * 16 + s];
#pragma unroll
      for (int off = 16; off > 0; off >>= 1) {
        float t = __shfl_down(v, off, 32);
        v = (s < 8) ? (v + t) : fmaxf(v, t);
      }
      if (lane == 0) s_scal[s] = v;
    }
  }
  __syncthreads();

  const float total = s_scal[0];
  const bool has = total > 0.f;
  const float safe = fmaxf(total, 1.f);
  const float kf = fmaxf(1.f, rintf(total * 0.1f));

  // Phase B: waves 0..4 each scan one channel's 512 bins from LDS.
  // lane owns 8 bins [base, base+7], base=(63-lane)*8 -> ascending lane =
  // descending value range.
  if (wv < CHN) {
    const int c = wv;
    const int base = (63 - lane) * 8;
    float cntv[8];
    float gc = 0.f, gs = 0.f;
    const uint4* hv = (const uint4*)s_hist;
#pragma unroll
    for (int q = 0; q < 2; ++q) {
      uint4 u = hv[c * (NB / 4) + (63 - lane) * 2 + q];
      float c0 = (float)u.x, c1 = (float)u.y, c2 = (float)u.z, c3 = (float)u.w;
      int bin = base + q * 4;
      cntv[q * 4 + 0] = c0; cntv[q * 4 + 1] = c1;
      cntv[q * 4 + 2] = c2; cntv[q * 4 + 3] = c3;
      gc += c0 + c1 + c2 + c3;
      gs += c0 * ((bin + 0.5f) * (1.f / NB)) + c1 * ((bin + 1.5f) * (1.f / NB)) +
            c2 * ((bin + 2.5f) * (1.f / NB)) + c3 * ((bin + 3.5f) * (1.f / NB));
    }
    // inclusive scan over lanes (lane 0 = topmost bins)
    float ic = gc, is = gs;
#pragma unroll
    for (int off = 1; off < 64; off <<= 1) {
      float tc = __shfl_up(ic, off);
      float ts = __shfl_up(is, off);
      if (lane >= off) { ic += tc; is += ts; }
    }
    float ec = ic - gc;   // count strictly above this lane's bins
    float es = is - gs;   // center-weighted sum strictly above

    if (has && ec < kf && kf <= ic) {
      float cg = ec, ss = es;
#pragma unroll
      for (int d = 7; d >= 0; --d) {
        int bin = base + d;
        float center = (bin + 0.5f) * (1.f / NB);
        float cb = cntv[d];
        if (cg + cb >= kf) {
          float r = kf - cg;
          topk[c] = (ss + r * center) / kf;
          break;
        }
        cg += cb;
        ss += cb * center;
      }
    }
  }
  __syncthreads();

  if (tid == 0) {
    float inv_safe = 1.f / safe;
    stats[0] = s_scal[1] * inv_safe;
    stats[1] = s_scal[2] * inv_safe;
    stats[2] = s_scal[3] * inv_safe;
    stats[3] = s_scal[4] * inv_safe;
#pragma unroll
    for (int c = 0; c < 4; ++c) stats[4 + c] = has ? s_scal[8 + c] : 0.f;
#pragma unroll
    for (int c = 0; c < 4; ++c) stats[8 + c] = has ? topk[c] : 0.f;
    stats[12] = has ? s_scal[5] * inv_safe : 0.f;
    stats[13] = has ? s_scal[12] : 0.f;
    stats[14] = has ? topk[4] : 0.f;
    stats[15] = has ? s_scal[6] * inv_safe : 0.f;
    stats[16] = has ? s_scal[7] * inv_safe : 0.f;
    stats[17] = has ? total * (1.f / (float)kN) : 0.f;

    float mu = 0.f;
#pragma unroll
    for (int i = 0; i < 18; ++i) mu += stats[i];
    mu *= (1.f / 18.f);
    float var = 0.f;
#pragma unroll
    for (int i = 0; i < 18; ++i) {
      float d = stats[i] - mu;
      var += d * d;
    }
    var *= (1.f / 18.f);
    float inv_std = rsqrtf(var + 1e-5f);
#pragma unroll
    for (int i = 0; i < 18; ++i)
      normed[i] = (stats[i] - mu) * inv_std * ln_w[i] + ln_b[i];
  }
  __syncthreads();

  // Phase D (threads 0..255): h1 = gelu_exact(normed @ w1 + b1), then
  // projected = h1 @ w2 + b2
  if (tid < 256) {
    float x = b1[tid];
#pragma unroll
    for (int i = 0; i < 18; ++i) x += normed[i] * w1[i * 256 + tid];
    h1v[tid] = 0.5f * x * (1.f + erff(x * 0.70710678118654752440f));
  }
  __syncthreads();
  if (tid < 256) {
    float y = b2[tid];
    for (int i = 0; i < 256; ++i) y += h1v[i] * w2[i * 256 + tid];

    // outputs: stats[16][18] | projected[16][256] | damaged[16] | high[16] | tar[16]
    out[288 + b * 256 + tid] = y;
    if (tid < 18) out[b * 18 + tid] = stats[tid];
    if (tid == 0) {
      out[4384 + b] = stats[15];
      out[4400 + b] = stats[16];
      out[4416 + b] = stats[17];
    }
  }
}

extern "C" void kernel_launch(void* const* d_in, const int* in_sizes, int n_in,
                              void* d_out, int out_size, void* d_ws, size_t ws_size,
                              hipStream_t stream) {
  const float* logits = (const float*)d_in[0];
  const float* sevmap = (const float*)d_in[1];
  const float* maskp  = (const float*)d_in[2];
  const float* ln_w   = (const float*)d_in[3];
  const float* ln_b   = (const float*)d_in[4];
  const float* w1     = (const float*)d_in[5];
  const float* b1     = (const float*)d_in[6];
  const float* w2     = (const float*)d_in[7];
  const float* b2     = (const float*)d_in[8];
  float* out = (float*)d_out;

  char* ws = (char*)d_ws;
  float* spart = (float*)(ws + SPART_OFF);
  unsigned short* part_hist = (unsigned short*)(ws + PART_OFF);

  dim3 g1(kChunks, kB);
  ep_pass1<<<g1, kThreads1, 0, stream>>>(logits, sevmap, maskp, spart, part_hist);
  ep_finalize<<<kB, 1024, 0, stream>>>(spart, part_hist, ln_w, ln_b, w1, b1, w2,
                                       b2, out);
}